// Round 9
// baseline (131.125 us; speedup 1.0000x reference)
//
#include <hip/hip_runtime.h>

// RPN anchor-target assignment. B=8, A=184320, G=64.
// Outputs (flat float32, concatenated): labels[B*A], matched[B*A*4], max_iou[B*A].
// Requires A % 512 == 0 (184320 = 360*512).
//
// Sparse-mask strategy, 2 anchors/thread FUSED in one interleaved loop (two
// independent IoU dependency chains per iteration -> 2x ILP; R8 showed 25%
// latency-idle from the serial ds_read->minmax->IEEE-div chain). Per batch,
// 4 quantized interval tables (u64[256], 2.5px strips, slack 0.01) give each
// anchor a conservative superset mask of possibly-overlapping gts. Skipped
// pairs have true iou==0, handled exactly by maxv init 0 / KEY_INIT. gt
// coords SoA in LDS; column argmax via LDS u64 atomicMax (branchless zero-key
// when invalid/zero); block->global via device atomicMax on signed i64
// (d_ws 0xAA poison is negative == -inf, no init kernel). No device fences
// (R6: per-block __threadfence() is an L2-flush-scale stall on CDNA4).

constexpr int B = 8;
constexpr int G = 64;
constexpr int BLOCK = 256;
constexpr int APT = 2;                 // anchors per thread (fused)
constexpr int ABLK = BLOCK * APT;      // anchors per block
constexpr int NSTRIP = 256;            // 2.5px strips
constexpr float STRIP_SCALE = 0.4f;
constexpr float STRIP_W = 2.5f;
constexpr float IMG = 640.0f;
constexpr float FG_IOU = 0.7f;
constexpr float BG_IOU = 0.3f;
constexpr float SLACK = 0.01f;         // covers ~1e-4px strip-assign rounding only
// key(iou=0, anchor=0): correct for an all-zero column (numpy argmax = 0).
constexpr unsigned long long KEY_INIT = 0xFFFFFFFFull;

// ws layout: [256]   i64 gkeys[B*G]       (0xAA poison < 0 as i64 == -inf)
//            [8192]  u64 tabs[B][4][256]  (built by build_tables each launch)

// tab0 (xlo): gt.x0 < (s+1)*2.5 + SLACK  used at s=strip(ax1)  ⊇ gt.x0 < ax1
// tab1 (xhi): gt.x1 > s*2.5 - SLACK      used at s=strip(ax0)  ⊇ gt.x1 > ax0
// tab2 (ylo): gt.y0 < (s+1)*2.5 + SLACK  used at s=strip(ay1)  ⊇ gt.y0 < ay1
// tab3 (yhi): gt.y1 > s*2.5 - SLACK      used at s=strip(ay0)  ⊇ gt.y1 > ay0
__global__ __launch_bounds__(1024) void build_tables(
    const float4* __restrict__ gt, unsigned long long* __restrict__ tabs) {
    __shared__ float4 sgt[G];
    const int b = blockIdx.x;
    const int t = threadIdx.x;          // 0..1023 = tabIdx*256 + strip
    if (t < G) sgt[t] = gt[b * G + t];
    __syncthreads();
    const int tabIdx = t >> 8;
    const int strip = t & 255;
    const int comp = (tabIdx == 0) ? 0 : (tabIdx == 1) ? 2 : (tabIdx == 2) ? 1 : 3;
    const bool hi = (tabIdx & 1) != 0;
    const float thr = hi ? (strip * STRIP_W - SLACK)
                         : ((strip + 1) * STRIP_W + SLACK);
    unsigned long long m = 0ull;
    for (int g = 0; g < G; ++g) {
        float c = ((const float*)&sgt[g])[comp];
        bool in = hi ? (c > thr) : (c < thr);
        if (in) m |= (1ull << g);
    }
    tabs[(size_t)b * 1024 + t] = m;
}

__global__ __launch_bounds__(BLOCK) void assign_main(
    const float4* __restrict__ anchors,   // [B*A] cxcywh
    const float4* __restrict__ gt,        // [B*G] xyxy
    float* __restrict__ L,                // labels out [B*A]
    float4* __restrict__ M,               // matched out [B*A]
    float* __restrict__ V,                // max_iou out [B*A]
    long long* __restrict__ gkeys,        // [B*G] global argmax keys (signed max)
    const unsigned long long* __restrict__ tabs,
    int A, int bpb) {
#pragma clang fp contract(off)
    __shared__ float4 sgt[G];             // AoS for the rare fg epilogue read
    __shared__ float sgx0[G], sgy0[G], sgx1[G], sgy1[G], sga[G];
    __shared__ unsigned long long tab[4][NSTRIP];
    __shared__ unsigned long long skey[G];

    const int b = blockIdx.x / bpb;
    const int t = threadIdx.x;
    const int base = (blockIdx.x % bpb) * ABLK;

    if (t < G) {
        float4 gb = gt[b * G + t];
        sgt[t] = gb;
        sgx0[t] = gb.x; sgy0[t] = gb.y; sgx1[t] = gb.z; sgy1[t] = gb.w;
        sga[t] = (gb.z - gb.x) * (gb.w - gb.y);
        skey[t] = KEY_INIT;
    }
    {   // 8 KB table: four u64 per thread
        unsigned long long* tflat = &tab[0][0];
        const unsigned long long* src = tabs + (size_t)b * 1024;
        tflat[t]       = src[t];
        tflat[t + 256] = src[t + 256];
        tflat[t + 512] = src[t + 512];
        tflat[t + 768] = src[t + 768];
    }
    __syncthreads();

    // ---- two anchors, fused ----
    const int a0 = base + t;
    const int a1 = base + BLOCK + t;
    const size_t idx0 = (size_t)b * A + a0;
    const size_t idx1 = (size_t)b * A + a1;
    float4 an0 = anchors[idx0];
    float4 an1 = anchors[idx1];

    float p0x0 = an0.x - 0.5f * an0.z, p0y0 = an0.y - 0.5f * an0.w;
    float p0x1 = an0.x + 0.5f * an0.z, p0y1 = an0.y + 0.5f * an0.w;
    float p1x0 = an1.x - 0.5f * an1.z, p1y0 = an1.y - 0.5f * an1.w;
    float p1x1 = an1.x + 0.5f * an1.z, p1y1 = an1.y + 0.5f * an1.w;
    float area0 = (p0x1 - p0x0) * (p0y1 - p0y0);
    float area1 = (p1x1 - p1x0) * (p1y1 - p1y0);

    auto stripc = [](float v) {
        int s = (int)(v * STRIP_SCALE);
        return s < 0 ? 0 : (s > NSTRIP - 1 ? NSTRIP - 1 : s);
    };
    unsigned long long m0 = tab[0][stripc(p0x1)] & tab[1][stripc(p0x0)] &
                            tab[2][stripc(p0y1)] & tab[3][stripc(p0y0)];
    unsigned long long m1 = tab[0][stripc(p1x1)] & tab[1][stripc(p1x0)] &
                            tab[2][stripc(p1y1)] & tab[3][stripc(p1y0)];

    float max0 = 0.0f, max1 = 0.0f;   // all-masked row => max_iou 0, argmax 0
    int mg0 = 0, mg1 = 0;
    const unsigned long long invp0 = (unsigned long long)(0xFFFFFFFFu - (unsigned)a0);
    const unsigned long long invp1 = (unsigned long long)(0xFFFFFFFFu - (unsigned)a1);

    while (m0 | m1) {
        const bool v0 = (m0 != 0ull), v1 = (m1 != 0ull);
        const int g0 = v0 ? (__ffsll(m0) - 1) : 0;   // clamp: guarded below
        const int g1 = v1 ? (__ffsll(m1) - 1) : 0;
        m0 &= m0 - 1;
        m1 &= m1 - 1;

        // chain 0 and chain 1: independent — compiler interleaves for ILP
        float ga0x0 = sgx0[g0], ga0y0 = sgy0[g0], ga0x1 = sgx1[g0], ga0y1 = sgy1[g0];
        float ga1x0 = sgx0[g1], ga1y0 = sgy0[g1], ga1x1 = sgx1[g1], ga1y1 = sgy1[g1];
        float sa0 = sga[g0], sa1 = sga[g1];

        float w0 = fmaxf(fminf(p0x1, ga0x1) - fmaxf(p0x0, ga0x0), 0.0f);
        float h0 = fmaxf(fminf(p0y1, ga0y1) - fmaxf(p0y0, ga0y0), 0.0f);
        float w1 = fmaxf(fminf(p1x1, ga1x1) - fmaxf(p1x0, ga1x0), 0.0f);
        float h1 = fmaxf(fminf(p1y1, ga1y1) - fmaxf(p1y0, ga1y0), 0.0f);
        float in0 = w0 * h0, in1 = w1 * h1;
        float iou0 = in0 / (area0 + sa0 - in0);   // IEEE div: bit-exact vs numpy
        float iou1 = in1 / (area1 + sa1 - in1);

        // row argmax (ascending g per chain: strict > keeps numpy first-max)
        bool b0 = v0 && (iou0 > max0);
        bool b1 = v1 && (iou1 > max1);
        max0 = b0 ? iou0 : max0;  mg0 = b0 ? g0 : mg0;
        max1 = b1 ? iou1 : max1;  mg1 = b1 ? g1 : mg1;

        // column argmax: branchless zero key when invalid or iou==0
        unsigned long long k0 =
            ((unsigned long long)__float_as_uint(iou0) << 32) | invp0;
        unsigned long long k1 =
            ((unsigned long long)__float_as_uint(iou1) << 32) | invp1;
        k0 = (v0 && iou0 > 0.0f) ? k0 : 0ull;
        k1 = (v1 && iou1 > 0.0f) ? k1 : 0ull;
        atomicMax(&skey[g0], k0);
        atomicMax(&skey[g1], k1);
    }

    {   // epilogue anchor 0
        bool fg = max0 > FG_IOU, bg = max0 < BG_IOU;
        bool cross = (p0x0 < 0.0f) || (p0y0 < 0.0f) || (p0x1 > IMG) || (p0y1 > IMG);
        L[idx0] = cross ? -1.0f : (fg ? 1.0f : (bg ? 0.0f : -1.0f));
        M[idx0] = fg ? sgt[mg0] : make_float4(0.0f, 0.0f, 0.0f, 0.0f);
        V[idx0] = max0;
    }
    {   // epilogue anchor 1
        bool fg = max1 > FG_IOU, bg = max1 < BG_IOU;
        bool cross = (p1x0 < 0.0f) || (p1y0 < 0.0f) || (p1x1 > IMG) || (p1y1 > IMG);
        L[idx1] = cross ? -1.0f : (fg ? 1.0f : (bg ? 0.0f : -1.0f));
        M[idx1] = fg ? sgt[mg1] : make_float4(0.0f, 0.0f, 0.0f, 0.0f);
        V[idx1] = max1;
    }

    __syncthreads();
    if (t < G) {
        // unconditional: every column must receive >= KEY_INIT (gkeys poisoned)
        atomicMax(&gkeys[b * G + t], (long long)skey[t]);
    }
}

// Rule 1 fixup: one block per batch, thread per gt. numpy scatter is
// last-write-wins; thread g writes only if no later g' targets the same anchor.
__global__ void fixup(
    const float4* __restrict__ anchors,
    const float4* __restrict__ gt,
    const long long* __restrict__ gkeys,
    float* __restrict__ L,
    float4* __restrict__ M,
    const float* __restrict__ V,
    int A) {
#pragma clang fp contract(off)
    const int b = blockIdx.x;
    const int g = threadIdx.x;
    __shared__ int tgt[G];

    unsigned long long key = (unsigned long long)gkeys[b * G + g];
    unsigned int a = 0xFFFFFFFFu - (unsigned int)(key & 0xFFFFFFFFull);
    tgt[g] = (int)a;
    __syncthreads();

    bool write = true;
    for (int g2 = g + 1; g2 < G; ++g2)
        if (tgt[g2] == (int)a) { write = false; break; }
    if (!write) return;

    const size_t idx = (size_t)b * A + a;
    float4 an = anchors[idx];
    float ax0 = an.x - 0.5f * an.z;
    float ay0 = an.y - 0.5f * an.w;
    float ax1 = an.x + 0.5f * an.z;
    float ay1 = an.y + 0.5f * an.w;
    bool cross = (ax0 < 0.0f) || (ay0 < 0.0f) || (ax1 > IMG) || (ay1 > IMG);
    // Rule 1 label=1 overrides rule-3 bg; cross filter still wins.
    L[idx] = cross ? -1.0f : 1.0f;
    // Rule 2 (fg) overrides rule 1's matched box; otherwise rule 1 assigns gt[g].
    if (!(V[idx] > FG_IOU)) M[idx] = gt[b * G + g];
}

extern "C" void kernel_launch(void* const* d_in, const int* in_sizes, int n_in,
                              void* d_out, int out_size, void* d_ws, size_t ws_size,
                              hipStream_t stream) {
    const float4* anchors = (const float4*)d_in[0];
    const float4* gt      = (const float4*)d_in[1];
    const int A = in_sizes[0] / (B * 4);

    float* out = (float*)d_out;
    float*  L = out;                                 // [B*A]
    float4* M = (float4*)(out + (size_t)B * A);      // [B*A] float4
    float*  V = out + (size_t)B * A * 5;             // [B*A]

    char* ws = (char*)d_ws;
    long long* gkeys = (long long*)(ws + 256);       // poison 0xAA.. == -inf (i64)
    unsigned long long* tabs = (unsigned long long*)(ws + 8192);  // B*4*256 u64

    const int bpb = A / ABLK;                        // 184320/512 = 360
    build_tables<<<B, 1024, 0, stream>>>(gt, tabs);
    assign_main<<<B * bpb, BLOCK, 0, stream>>>(anchors, gt, L, M, V, gkeys,
                                               tabs, A, bpb);
    fixup<<<B, G, 0, stream>>>(anchors, gt, gkeys, L, M, V, A);
}

// Round 10
// 123.858 us; speedup vs baseline: 1.0587x; 1.0587x over previous
//
#include <hip/hip_runtime.h>

// RPN anchor-target assignment. B=8, A=184320, G=64.
// Outputs (flat float32, concatenated): labels[B*A], matched[B*A*4], max_iou[B*A].
// Requires A % 512 == 0 (184320 = 360*512).
//
// Sparse-mask strategy, 2 anchors/thread (SEQUENTIAL — R9 showed fusing the
// two chains doubles LDS conflicts and regresses), 3 kernels (no device
// fences — R6: per-block __threadfence() is an L2-flush-scale stall).
// Per batch, 4 quantized interval tables (u64[128], 5px strips, slack 0.01)
// give each anchor a conservative superset mask of possibly-overlapping gts;
// the exact IEEE IoU loop runs only over mask bits (~10 avg) in ONE u64 loop
// (single wave-max, vs two half-loop maxima in R8). Skipped pairs have true
// iou==0, handled exactly by row-key init 0 / KEY_INIT. gt coords as float2
// SoA in LDS (2x ds_read_b64 + 1x b32 = 3 DS ops/iter vs 5). Row argmax is a
// packed u64 max: (iou_bits<<32)|(63-g) — ties pick smaller g (numpy
// first-max); mg is only consumed when fg, so the maxv==0 case is inert.
// Column argmax via LDS u64 atomicMax (branchless zero key), block->global
// via device atomicMax on signed i64 (d_ws 0xAA poison < 0 == -inf).

constexpr int B = 8;
constexpr int G = 64;
constexpr int BLOCK = 256;
constexpr int APT = 2;                 // anchors per thread
constexpr int ABLK = BLOCK * APT;      // anchors per block
constexpr int NSTRIP = 128;            // 5px strips
constexpr float STRIP_SCALE = 0.2f;
constexpr float STRIP_W = 5.0f;
constexpr float IMG = 640.0f;
constexpr float FG_IOU = 0.7f;
constexpr float BG_IOU = 0.3f;
constexpr float SLACK = 0.01f;         // covers ~1e-4px strip-assign rounding
// key(iou=0, anchor=0): correct for an all-zero column (numpy argmax = 0).
constexpr unsigned long long KEY_INIT = 0xFFFFFFFFull;

// ws layout: [256]   i64 gkeys[B*G]      (0xAA poison < 0 as i64 == -inf)
//            [8192]  u64 tabs[B][4][128] (built by build_tables each launch)

// tab0 (xlo): gt.x0 < (s+1)*5 + SLACK   used at s=strip(ax1)  ⊇ gt.x0 < ax1
// tab1 (xhi): gt.x1 > s*5 - SLACK       used at s=strip(ax0)  ⊇ gt.x1 > ax0
// tab2 (ylo): gt.y0 < (s+1)*5 + SLACK   used at s=strip(ay1)  ⊇ gt.y0 < ay1
// tab3 (yhi): gt.y1 > s*5 - SLACK       used at s=strip(ay0)  ⊇ gt.y1 > ay0
__global__ __launch_bounds__(512) void build_tables(
    const float4* __restrict__ gt, unsigned long long* __restrict__ tabs) {
    __shared__ float4 sgt[G];
    const int b = blockIdx.x;
    const int t = threadIdx.x;          // 0..511 = tabIdx*128 + strip
    if (t < G) sgt[t] = gt[b * G + t];
    __syncthreads();
    const int tabIdx = t >> 7;
    const int strip = t & 127;
    const int comp = (tabIdx == 0) ? 0 : (tabIdx == 1) ? 2 : (tabIdx == 2) ? 1 : 3;
    const bool hi = (tabIdx & 1) != 0;
    const float thr = hi ? (strip * STRIP_W - SLACK)
                         : ((strip + 1) * STRIP_W + SLACK);
    unsigned long long m = 0ull;
    for (int g = 0; g < G; ++g) {
        float c = ((const float*)&sgt[g])[comp];
        bool in = hi ? (c > thr) : (c < thr);
        if (in) m |= (1ull << g);
    }
    tabs[(size_t)b * 512 + t] = m;
}

__global__ __launch_bounds__(BLOCK) void assign_main(
    const float4* __restrict__ anchors,   // [B*A] cxcywh
    const float4* __restrict__ gt,        // [B*G] xyxy
    float* __restrict__ L,                // labels out [B*A]
    float4* __restrict__ M,               // matched out [B*A]
    float* __restrict__ V,                // max_iou out [B*A]
    long long* __restrict__ gkeys,        // [B*G] global argmax keys (signed max)
    const unsigned long long* __restrict__ tabs,
    int A, int bpb) {
#pragma clang fp contract(off)
    __shared__ float4 sgt[G];             // AoS for the rare fg epilogue read
    __shared__ float2 sglo[G];            // (x0,y0)  -> ds_read_b64
    __shared__ float2 sghi[G];            // (x1,y1)  -> ds_read_b64
    __shared__ float sga[G];              // area     -> ds_read_b32
    __shared__ unsigned long long tab[4][NSTRIP];
    __shared__ unsigned long long skey[G];

    const int b = blockIdx.x / bpb;
    const int t = threadIdx.x;
    const int base = (blockIdx.x % bpb) * ABLK;

    if (t < G) {
        float4 gb = gt[b * G + t];
        sgt[t] = gb;
        sglo[t] = make_float2(gb.x, gb.y);
        sghi[t] = make_float2(gb.z, gb.w);
        sga[t] = (gb.z - gb.x) * (gb.w - gb.y);
        skey[t] = KEY_INIT;
    }
    {   // 4 KB table: two u64 per thread
        unsigned long long* tflat = &tab[0][0];
        const unsigned long long* src = tabs + (size_t)b * 512;
        tflat[t]       = src[t];
        tflat[t + 256] = src[t + 256];
    }
    __syncthreads();

#pragma unroll
    for (int j = 0; j < APT; ++j) {
        const int a = base + j * BLOCK + t;
        const size_t idx = (size_t)b * A + a;
        float4 an = anchors[idx];
        float ax0 = an.x - 0.5f * an.z;
        float ay0 = an.y - 0.5f * an.w;
        float ax1 = an.x + 0.5f * an.z;
        float ay1 = an.y + 0.5f * an.w;
        float area_a = (ax1 - ax0) * (ay1 - ay0);   // corner-derived, matches numpy

        int sx0 = (int)(ax0 * STRIP_SCALE); sx0 = sx0 < 0 ? 0 : (sx0 > 127 ? 127 : sx0);
        int sx1 = (int)(ax1 * STRIP_SCALE); sx1 = sx1 < 0 ? 0 : (sx1 > 127 ? 127 : sx1);
        int sy0 = (int)(ay0 * STRIP_SCALE); sy0 = sy0 < 0 ? 0 : (sy0 > 127 ? 127 : sy0);
        int sy1 = (int)(ay1 * STRIP_SCALE); sy1 = sy1 < 0 ? 0 : (sy1 > 127 ? 127 : sy1);

        unsigned long long mask =
            tab[0][sx1] & tab[1][sx0] & tab[2][sy1] & tab[3][sy0];

        // row argmax as packed u64 max: (iou_bits<<32)|(63-g).
        // init 0: all-masked row => maxv 0 (numpy: max of zero row), mg unused.
        unsigned long long rk = 0ull;
        const unsigned long long inv_p =
            (unsigned long long)(0xFFFFFFFFu - (unsigned)a);

        while (mask) {
            const int g = __builtin_ctzll(mask);   // ascending g
            mask &= mask - 1;
            float2 glo = sglo[g];
            float2 ghi = sghi[g];
            float sa = sga[g];
            float w = fmaxf(fminf(ax1, ghi.x) - fmaxf(ax0, glo.x), 0.0f);
            float h = fmaxf(fminf(ay1, ghi.y) - fmaxf(ay0, glo.y), 0.0f);
            float inter = w * h;
            float uni = area_a + sa - inter;
            float iou = inter / uni;               // IEEE div: bit-exact vs numpy

            // row: u64 max; equal iou -> larger (63-g) -> smaller g = first-max
            unsigned long long cand =
                ((unsigned long long)__float_as_uint(iou) << 32) |
                (unsigned long long)(63 - g);
            rk = (cand > rk) ? cand : rk;

            // column: branchless zero key when iou==0 (never beats KEY_INIT)
            unsigned long long key =
                ((unsigned long long)__float_as_uint(iou) << 32) | inv_p;
            key = (iou > 0.0f) ? key : 0ull;
            atomicMax(&skey[g], key);
        }

        float maxv = __uint_as_float((unsigned)(rk >> 32));
        int mg = 63 - (int)(rk & 63);

        bool fg = maxv > FG_IOU;
        bool bg = maxv < BG_IOU;
        bool cross = (ax0 < 0.0f) || (ay0 < 0.0f) || (ax1 > IMG) || (ay1 > IMG);

        L[idx] = cross ? -1.0f : (fg ? 1.0f : (bg ? 0.0f : -1.0f));
        M[idx] = fg ? sgt[mg] : make_float4(0.0f, 0.0f, 0.0f, 0.0f);
        V[idx] = maxv;
    }

    __syncthreads();
    if (t < G) {
        // unconditional: every column must receive >= KEY_INIT (gkeys poisoned)
        atomicMax(&gkeys[b * G + t], (long long)skey[t]);
    }
}

// Rule 1 fixup: one block per batch, thread per gt. numpy scatter is
// last-write-wins; thread g writes only if no later g' targets the same anchor.
__global__ void fixup(
    const float4* __restrict__ anchors,
    const float4* __restrict__ gt,
    const long long* __restrict__ gkeys,
    float* __restrict__ L,
    float4* __restrict__ M,
    const float* __restrict__ V,
    int A) {
#pragma clang fp contract(off)
    const int b = blockIdx.x;
    const int g = threadIdx.x;
    __shared__ int tgt[G];

    unsigned long long key = (unsigned long long)gkeys[b * G + g];
    unsigned int a = 0xFFFFFFFFu - (unsigned int)(key & 0xFFFFFFFFull);
    tgt[g] = (int)a;
    __syncthreads();

    bool write = true;
    for (int g2 = g + 1; g2 < G; ++g2)
        if (tgt[g2] == (int)a) { write = false; break; }
    if (!write) return;

    const size_t idx = (size_t)b * A + a;
    float4 an = anchors[idx];
    float ax0 = an.x - 0.5f * an.z;
    float ay0 = an.y - 0.5f * an.w;
    float ax1 = an.x + 0.5f * an.z;
    float ay1 = an.y + 0.5f * an.w;
    bool cross = (ax0 < 0.0f) || (ay0 < 0.0f) || (ax1 > IMG) || (ay1 > IMG);
    // Rule 1 label=1 overrides rule-3 bg; cross filter still wins.
    L[idx] = cross ? -1.0f : 1.0f;
    // Rule 2 (fg) overrides rule 1's matched box; otherwise rule 1 assigns gt[g].
    if (!(V[idx] > FG_IOU)) M[idx] = gt[b * G + g];
}

extern "C" void kernel_launch(void* const* d_in, const int* in_sizes, int n_in,
                              void* d_out, int out_size, void* d_ws, size_t ws_size,
                              hipStream_t stream) {
    const float4* anchors = (const float4*)d_in[0];
    const float4* gt      = (const float4*)d_in[1];
    const int A = in_sizes[0] / (B * 4);

    float* out = (float*)d_out;
    float*  L = out;                                 // [B*A]
    float4* M = (float4*)(out + (size_t)B * A);      // [B*A] float4
    float*  V = out + (size_t)B * A * 5;             // [B*A]

    char* ws = (char*)d_ws;
    long long* gkeys = (long long*)(ws + 256);       // poison 0xAA.. == -inf (i64)
    unsigned long long* tabs = (unsigned long long*)(ws + 8192);  // B*4*128 u64

    const int bpb = A / ABLK;                        // 184320/512 = 360
    build_tables<<<B, 512, 0, stream>>>(gt, tabs);
    assign_main<<<B * bpb, BLOCK, 0, stream>>>(anchors, gt, L, M, V, gkeys,
                                               tabs, A, bpb);
    fixup<<<B, G, 0, stream>>>(anchors, gt, gkeys, L, M, V, A);
}